// Round 8
// baseline (295.766 us; speedup 1.0000x reference)
//
#include <hip/hip_runtime.h>
#include <math.h>

#define BATCH 2
#define LSEQ  2048
#define DIMM  1024
#define NH    16
#define DH    64

typedef unsigned short ushortT;
typedef __attribute__((ext_vector_type(8))) short bf16x8;
typedef __attribute__((ext_vector_type(4))) float f32x4;

#define MFMA16(a, b, c) __builtin_amdgcn_mfma_f32_16x16x32_bf16((a), (b), (c), 0, 0, 0)

// scale folded into q columns of W_qkv: (1/sqrt(64)) * log2(e)
#define QSCALE 0.18033688011112042f

__device__ __forceinline__ ushortT f2bf(float f) {
    unsigned u = __float_as_uint(f);
    u += 0x7fffu + ((u >> 16) & 1u);   // RNE
    return (ushortT)(u >> 16);
}

// async global->LDS, 16B per lane. LDS dest is wave-uniform base + lane*16.
__device__ __forceinline__ void gll16(const ushortT* g, ushortT* l) {
    ushortT* gm = const_cast<ushortT*>(g);
    __builtin_amdgcn_global_load_lds(
        (__attribute__((address_space(1))) void*)gm,
        (__attribute__((address_space(3))) void*)l, 16, 0, 0);
}

// ---------------------------------------------------------------------------
// Fused prep: blocks [0,4096): x fp32->bf16; blocks [4096,8192): weight
// transposes W[K][N] fp32 -> Wt[N][K] bf16 (q-cols of W_qkv scaled by QSCALE).
// ---------------------------------------------------------------------------
__global__ __launch_bounds__(256) void prep(
    const float* __restrict__ x, ushortT* __restrict__ xb,
    const float* __restrict__ Wqkv, const float* __restrict__ Wout,
    ushortT* __restrict__ wqt, ushortT* __restrict__ wot)
{
    __shared__ float T[32][33];
    const int bx = blockIdx.x;
    const int tid = threadIdx.x;
    if (bx < 4096) {
        int i = bx * 256 + tid;
        float4 v = ((const float4*)x)[i];
        ushort4 o;
        o.x = f2bf(v.x); o.y = f2bf(v.y); o.z = f2bf(v.z); o.w = f2bf(v.w);
        ((ushort4*)xb)[i] = o;
        return;
    }
    const int id2 = bx - 4096;
    const int nb = id2 & 127, kb = id2 >> 7;
    const float* W; ushortT* Wt; int N, n0, nlimit;
    if (nb < 96) { W = Wqkv; Wt = wqt; N = 3 * DIMM; n0 = nb * 32; nlimit = DIMM; }
    else         { W = Wout; Wt = wot; N = DIMM;     n0 = (nb - 96) * 32; nlimit = 0; }
    const int k0 = kb * 32;
    const int c = tid & 31, r0 = tid >> 5;
#pragma unroll
    for (int p = 0; p < 4; ++p)
        T[r0 + 8 * p][c] = W[(size_t)(k0 + r0 + 8 * p) * N + n0 + c];
    __syncthreads();
#pragma unroll
    for (int p = 0; p < 4; ++p) {
        int rr = r0 + 8 * p;
        float v = T[c][rr];
        if (n0 + rr < nlimit) v *= QSCALE;
        Wt[(size_t)(n0 + rr) * DIMM + k0 + c] = f2bf(v);
    }
}

// ---------------------------------------------------------------------------
// 128x128 GEMM mainloop, REGISTER-PREFETCH staging: global->VGPR loads for
// tile k+1 issued before computing tile k from LDS; ds_write_b128 + barrier
// after compute. The vmcnt wait lands after the MFMA block (L2-warm loads
// ~200-250cyc -> hidden) instead of a cold drain before it (m97's ~500cyc
// per-iter stall). LDS layout identical to the DMA version.
// SWAP=false: acc rows = A(m) rows; SWAP=true: acc rows = Bt(n) rows (C^T).
// ---------------------------------------------------------------------------
template<bool SWAP>
__device__ __forceinline__ void mainloop128(
    const ushortT* __restrict__ A, const ushortT* __restrict__ Bt,
    ushortT* As, ushortT* Bs, int bm, int bn,
    int w, int lane, int quad, int li, f32x4 acc[4][4])
{
    const int wr = (w & 1) * 64, wc = (w >> 1) * 64;
    const int rsub = lane >> 3, csub = lane & 7;
    const int cch = csub ^ rsub;           // swizzled source chunk
    const int sw = li & 7;
    const int s0 = (quad ^ sw) * 8;
    const int s1 = ((quad + 4) ^ sw) * 8;

    const ushortT* pa[4]; const ushortT* pb[4];
    ushortT* la[4]; ushortT* lb[4];
#pragma unroll
    for (int j = 0; j < 4; ++j) {
        int r = (w * 4 + j) * 8 + rsub;
        pa[j] = A  + (size_t)(bm + r) * DIMM + cch * 8;
        pb[j] = Bt + (size_t)(bn + r) * DIMM + cch * 8;
        la[j] = As + (w * 4 + j) * 512 + lane * 8;   // lane's own 16B slot
        lb[j] = Bs + (w * 4 + j) * 512 + lane * 8;
    }
    const ushortT* RS = SWAP ? Bs : As;    // row-operand source
    const ushortT* CS = SWAP ? As : Bs;    // col-operand source

    uint4 ra[4], rb[4];
#pragma unroll
    for (int j = 0; j < 4; ++j) {          // prologue: tile 0
        ra[j] = *(const uint4*)pa[j]; rb[j] = *(const uint4*)pb[j];
        pa[j] += 64; pb[j] += 64;
    }
#pragma unroll
    for (int j = 0; j < 4; ++j) {
        *(uint4*)la[j] = ra[j]; *(uint4*)lb[j] = rb[j];
    }
    __syncthreads();

    for (int k0 = 0; k0 < DIMM; k0 += 64) {
        const bool more = (k0 + 64 < DIMM);
        if (more) {
#pragma unroll
            for (int j = 0; j < 4; ++j) {  // prefetch k+1 (in flight over MFMA)
                ra[j] = *(const uint4*)pa[j]; rb[j] = *(const uint4*)pb[j];
                pa[j] += 64; pb[j] += 64;
            }
        }
        bf16x8 bfr[4][2];
#pragma unroll
        for (int t = 0; t < 4; ++t) {
            int R = wc + 16 * t + li;
            bfr[t][0] = *(const bf16x8*)&CS[R * 64 + s0];
            bfr[t][1] = *(const bf16x8*)&CS[R * 64 + s1];
        }
#pragma unroll
        for (int rt = 0; rt < 4; ++rt) {
            int R = wr + 16 * rt + li;
            bf16x8 a0 = *(const bf16x8*)&RS[R * 64 + s0];
            bf16x8 a1 = *(const bf16x8*)&RS[R * 64 + s1];
#pragma unroll
            for (int ct = 0; ct < 4; ++ct) {
                acc[rt][ct] = MFMA16(a0, bfr[ct][0], acc[rt][ct]);
                acc[rt][ct] = MFMA16(a1, bfr[ct][1], acc[rt][ct]);
            }
        }
        if (more) {
            __syncthreads();               // all readers of tile k done
#pragma unroll
            for (int j = 0; j < 4; ++j) {  // vmcnt wait here (post-MFMA)
                *(uint4*)la[j] = ra[j]; *(uint4*)lb[j] = rb[j];
            }
            __syncthreads();               // tile k+1 visible
        }
    }
}

// ---------------------------------------------------------------------------
// GEMM1: qkv projection. q/k via swapped mainloop -> vectorized [b,h,l,d]
// stores; v via normal mainloop -> vectorized transposed [b,h,d,l] stores.
// ---------------------------------------------------------------------------
__global__ __launch_bounds__(256) void gemm_qkv(
    const ushortT* __restrict__ A, const ushortT* __restrict__ Bt,
    const float* __restrict__ bias,
    ushortT* __restrict__ qb, ushortT* __restrict__ kb, ushortT* __restrict__ vt)
{
    __shared__ __align__(16) ushortT As[128 * 64];
    __shared__ __align__(16) ushortT Bs[128 * 64];
    const int tid = threadIdx.x;
    const int w = tid >> 6, lane = tid & 63, quad = lane >> 4, li = lane & 15;
    const int bm = blockIdx.y * 128, bn = blockIdx.x * 128;
    const int wr = (w & 1) * 64, wc = (w >> 1) * 64;
    const int which = bn >> 10;                       // 0=q 1=k 2=v (uniform)
    const f32x4 z4 = {0.f, 0.f, 0.f, 0.f};
    f32x4 acc[4][4];
#pragma unroll
    for (int i = 0; i < 4; ++i)
#pragma unroll
        for (int j = 0; j < 4; ++j) acc[i][j] = z4;

    if (which == 2) {
        mainloop128<false>(A, Bt, As, Bs, bm, bn, w, lane, quad, li, acc);
#pragma unroll
        for (int rt = 0; rt < 4; ++rt) {
            int m = bm + wr + 16 * rt + quad * 4;
            int b = m >> 11, l = m & 2047;
#pragma unroll
            for (int ct = 0; ct < 4; ++ct) {
                int n = bn + wc + 16 * ct + li;
                float bterm = bias[n];
                int h = (n >> 6) & 15, dd = n & 63;
                ushort4 o4;
                o4.x = f2bf(acc[rt][ct][0] + bterm);
                o4.y = f2bf(acc[rt][ct][1] + bterm);
                o4.z = f2bf(acc[rt][ct][2] + bterm);
                o4.w = f2bf(acc[rt][ct][3] + bterm);
                *(ushort4*)(vt + ((size_t)(b * NH + h) * DH + dd) * LSEQ + l) = o4;
            }
        }
    } else {
        mainloop128<true>(A, Bt, As, Bs, bm, bn, w, lane, quad, li, acc);
        const float bscale = (which == 0) ? QSCALE : 1.0f;
        ushortT* dst = (which == 0) ? qb : kb;
#pragma unroll
        for (int rt = 0; rt < 4; ++rt) {
            int n0 = bn + wr + 16 * rt + quad * 4;   // 4 consecutive n
            int h = (n0 >> 6) & 15, dd = n0 & 63;
            float4 bv = *(const float4*)&bias[n0];
#pragma unroll
            for (int ct = 0; ct < 4; ++ct) {
                int m = bm + wc + 16 * ct + li;
                int b = m >> 11, l = m & 2047;
                ushort4 o4;
                o4.x = f2bf(acc[rt][ct][0] + bv.x * bscale);
                o4.y = f2bf(acc[rt][ct][1] + bv.y * bscale);
                o4.z = f2bf(acc[rt][ct][2] + bv.z * bscale);
                o4.w = f2bf(acc[rt][ct][3] + bv.w * bscale);
                *(ushort4*)(dst + ((size_t)(b * NH + h) * LSEQ + l) * DH + dd) = o4;
            }
        }
    }
}

// ---------------------------------------------------------------------------
// GEMM2: out = o @ W_out + b_out (fp32 out). 128(M)x64(N) tiles, BK=128,
// register-prefetch staging (same rationale as mainloop128).
// ---------------------------------------------------------------------------
__global__ __launch_bounds__(256) void gemm_out(
    const ushortT* __restrict__ A, const ushortT* __restrict__ Bt,
    const float* __restrict__ bias, float* __restrict__ out)
{
    __shared__ __align__(16) ushortT As[128 * 128];   // 32 KB
    __shared__ __align__(16) ushortT Bs[64 * 128];    // 16 KB
    const int tid = threadIdx.x;
    const int w = tid >> 6, lane = tid & 63, quad = lane >> 4, li = lane & 15;
    const int bm = blockIdx.y * 128, bn = blockIdx.x * 64;
    const int wm = (w & 1) * 64, wn = (w >> 1) * 32;
    const int r4 = lane >> 4, c16 = lane & 15;
    const int sw = li & 7;

    const ushortT* pa[8]; ushortT* la[8];
#pragma unroll
    for (int j = 0; j < 8; ++j) {
        int Bi = w + 4 * j;
        int row = Bi * 4 + r4;
        int cxA = c16 ^ ((Bi & 1) * 4 + r4);       // == c16 ^ (row&7)
        pa[j] = A + (size_t)(bm + row) * DIMM + cxA * 8;
        la[j] = As + Bi * 512 + lane * 8;
    }
    const ushortT* pb[4]; ushortT* lb[4];
#pragma unroll
    for (int j = 0; j < 4; ++j) {
        int Bi = w + 4 * j;
        int row = Bi * 4 + r4;
        int cxB = c16 ^ ((Bi & 1) * 4 + r4);
        pb[j] = Bt + (size_t)(bn + row) * DIMM + cxB * 8;
        lb[j] = Bs + Bi * 512 + lane * 8;
    }

    const f32x4 z4 = {0.f, 0.f, 0.f, 0.f};
    f32x4 acc[4][2];
#pragma unroll
    for (int i = 0; i < 4; ++i) { acc[i][0] = z4; acc[i][1] = z4; }

    uint4 ra[8], rb[4];
#pragma unroll
    for (int j = 0; j < 8; ++j) { ra[j] = *(const uint4*)pa[j]; pa[j] += 128; }
#pragma unroll
    for (int j = 0; j < 4; ++j) { rb[j] = *(const uint4*)pb[j]; pb[j] += 128; }
#pragma unroll
    for (int j = 0; j < 8; ++j) *(uint4*)la[j] = ra[j];
#pragma unroll
    for (int j = 0; j < 4; ++j) *(uint4*)lb[j] = rb[j];
    __syncthreads();

    for (int k0 = 0; k0 < DIMM; k0 += 128) {
        const bool more = (k0 + 128 < DIMM);
        if (more) {
#pragma unroll
            for (int j = 0; j < 8; ++j) { ra[j] = *(const uint4*)pa[j]; pa[j] += 128; }
#pragma unroll
            for (int j = 0; j < 4; ++j) { rb[j] = *(const uint4*)pb[j]; pb[j] += 128; }
        }
#pragma unroll
        for (int g = 0; g < 2; ++g) {
            const int s0 = (g * 8 + (quad ^ sw)) * 8;
            const int s1 = (g * 8 + ((quad + 4) ^ sw)) * 8;
            bf16x8 bfr[2][2];
#pragma unroll
            for (int t = 0; t < 2; ++t) {
                int R = wn + 16 * t + li;
                bfr[t][0] = *(const bf16x8*)&Bs[R * 128 + s0];
                bfr[t][1] = *(const bf16x8*)&Bs[R * 128 + s1];
            }
#pragma unroll
            for (int rt = 0; rt < 4; ++rt) {
                int R = wm + 16 * rt + li;
                bf16x8 a0 = *(const bf16x8*)&As[R * 128 + s0];
                bf16x8 a1 = *(const bf16x8*)&As[R * 128 + s1];
#pragma unroll
                for (int ct = 0; ct < 2; ++ct) {
                    acc[rt][ct] = MFMA16(a0, bfr[ct][0], acc[rt][ct]);
                    acc[rt][ct] = MFMA16(a1, bfr[ct][1], acc[rt][ct]);
                }
            }
        }
        if (more) {
            __syncthreads();
#pragma unroll
            for (int j = 0; j < 8; ++j) *(uint4*)la[j] = ra[j];
#pragma unroll
            for (int j = 0; j < 4; ++j) *(uint4*)lb[j] = rb[j];
            __syncthreads();
        }
    }
#pragma unroll
    for (int rt = 0; rt < 4; ++rt) {
#pragma unroll
        for (int ct = 0; ct < 2; ++ct) {
            int n = bn + wn + 16 * ct + li;
            float bterm = bias[n];
#pragma unroll
            for (int r = 0; r < 4; ++r) {
                int m = bm + wm + 16 * rt + quad * 4 + r;
                out[(size_t)m * DIMM + n] = acc[rt][ct][r] + bterm;
            }
        }
    }
}

// ---------------------------------------------------------------------------
// Flash attention, block-causal, transposed inner math, 128-KEY TILES:
// one barrier per full 128-key causal chunk. DMA (global_load_lds) staging
// kept here: the t+1 DMA is issued before ~600cyc of compute, so its drain
// at the barrier is mostly covered. LDS 72 KB -> 2 blocks/CU. Grid 512,
// anti-correlated qt order -> CU pairs sum to ~36 subchunks.
// ---------------------------------------------------------------------------
__global__ __launch_bounds__(256, 2) void attn(
    const ushortT* __restrict__ qg, const ushortT* __restrict__ kg,
    const ushortT* __restrict__ vtg, ushortT* __restrict__ og)
{
    __shared__ __align__(16) ushortT Kbuf[2][8192];   // [p][half*4096 + blk*512]
    __shared__ __align__(16) ushortT Vbuf[2][8192];   // [d][l] halves
    __shared__ __align__(16) ushortT PsT[4096];       // 4 waves x 2 KB

    const int tid = threadIdx.x;
    const int w = tid >> 6, lane = tid & 63, quad = lane >> 4, li = lane & 15;
    const int id = blockIdx.x;                 // 0..511
    const int qt = (id < 256) ? (15 - (id >> 5)) : ((id - 256) >> 5);
    const int bhid = id & 31;
    const int b = bhid >> 4, h = bhid & 15;
    const size_t bh = (size_t)b * NH + h;
    const ushortT* qbase = qg + (bh * LSEQ + qt * 128) * DH;
    const ushortT* kbase = kg + bh * LSEQ * DH;
    const ushortT* vbase = vtg + bh * DH * LSEQ;
    ushortT* obase = og + ((size_t)b * LSEQ + qt * 128) * DIMM + h * DH;
    const f32x4 z4 = {0.f, 0.f, 0.f, 0.f};

    // staging lane geometry (within each 8-row x 1KB DMA block)
    const int r8 = lane >> 3, c8 = lane & 7, cx = c8 ^ r8;

    bf16x8 qf[2][2];
#pragma unroll
    for (int band = 0; band < 2; ++band) {
        int row = 32 * w + 16 * band + li;
        qf[band][0] = *(const bf16x8*)(qbase + (size_t)row * DH + quad * 8);
        qf[band][1] = *(const bf16x8*)(qbase + (size_t)row * DH + 32 + quad * 8);
    }
    f32x4 oaccT[2][4];     // [band][dt]: O^T, lane owns qrow=li
    float lacc[2];
#pragma unroll
    for (int i = 0; i < 2; ++i) {
        lacc[i] = 0.f;
#pragma unroll
        for (int j = 0; j < 4; ++j) oaccT[i][j] = z4;
    }

    const int nt = qt + 1;                 // 128-key tiles
    // stage tile 0 (8 gll16/wave: 2 halves x {K,V} x 2 blocks)
#pragma unroll
    for (int s = 0; s < 2; ++s)
#pragma unroll
        for (int jj = 0; jj < 2; ++jj) {
            int B = w + 4 * jj;
            gll16(kbase + (size_t)(s * 64 + B * 8 + r8) * DH + cx * 8,
                  &Kbuf[0][s * 4096 + B * 512]);
            gll16(vbase + (size_t)(B * 8 + r8) * LSEQ + s * 64 + cx * 8,
                  &Vbuf[0][s * 4096 + B * 512]);
        }
    __syncthreads();

    const int sw = li & 7;
    const int pbase = w * 1024 + li * 8;

    for (int t = 0; t < nt; ++t) {
        const int p = t & 1;
        if (t + 1 < nt) {   // DMA next 128-key tile; drains at loop barrier
#pragma unroll
            for (int s = 0; s < 2; ++s)
#pragma unroll
                for (int jj = 0; jj < 2; ++jj) {
                    int B = w + 4 * jj;
                    gll16(kbase + (size_t)((t + 1) * 128 + s * 64 + B * 8 + r8) * DH + cx * 8,
                          &Kbuf[1 - p][s * 4096 + B * 512]);
                    gll16(vbase + (size_t)(B * 8 + r8) * LSEQ + (t + 1) * 128 + s * 64 + cx * 8,
                          &Vbuf[1 - p][s * 4096 + B * 512]);
                }
        }

#pragma unroll
        for (int s = 0; s < 2; ++s) {
            const ushortT* Kb = &Kbuf[p][s * 4096];
            const ushortT* Vb = &Vbuf[p][s * 4096];
            bf16x8 kf[4][2], vf[4][2];
#pragma unroll
            for (int ct = 0; ct < 4; ++ct) {
                int R = 16 * ct + li;
                kf[ct][0] = *(const bf16x8*)&Kb[R * 64 + (quad ^ sw) * 8];
                kf[ct][1] = *(const bf16x8*)&Kb[R * 64 + ((quad + 4) ^ sw) * 8];
            }
#pragma unroll
            for (int dt = 0; dt < 4; ++dt) {
                int R = 16 * dt + li;
                vf[dt][0] = *(const bf16x8*)&Vb[R * 64 + (quad ^ sw) * 8];
                vf[dt][1] = *(const bf16x8*)&Vb[R * 64 + ((quad + 4) ^ sw) * 8];
            }
#pragma unroll
            for (int band = 0; band < 2; ++band) {
                // S^T = K Q^T (pre-scaled, log2 domain)
                f32x4 sa[4];
#pragma unroll
                for (int ct = 0; ct < 4; ++ct) {
                    sa[ct] = MFMA16(kf[ct][0], qf[band][0], z4);
                    sa[ct] = MFMA16(kf[ct][1], qf[band][1], sa[ct]);
                }
                // exp2, truncation-consistent sums, packed P^T write
#pragma unroll
                for (int ct = 0; ct < 4; ++ct) {
                    unsigned u[4];
#pragma unroll
                    for (int r = 0; r < 4; ++r) {
                        float pv = __builtin_amdgcn_exp2f(sa[ct][r]);
                        u[r] = __float_as_uint(pv);
                        lacc[band] += __uint_as_float(u[r] & 0xffff0000u);
                    }
                    uint2 pk;
                    pk.x = (u[1] & 0xffff0000u) | (u[0] >> 16);
                    pk.y = (u[3] & 0xffff0000u) | (u[2] >> 16);
                    *(uint2*)&PsT[pbase + (2 * ct + (quad >> 1)) * 128 + (quad & 1) * 4] = pk;
                }
                // O^T += V^T P^T (wave-private region; same-wave DS order)
                bf16x8 pt0 = *(const bf16x8*)&PsT[pbase + quad * 128];
                bf16x8 pt1 = *(const bf16x8*)&PsT[pbase + (4 + quad) * 128];
#pragma unroll
                for (int dt = 0; dt < 4; ++dt) {
                    oaccT[band][dt] = MFMA16(vf[dt][0], pt0, oaccT[band][dt]);
                    oaccT[band][dt] = MFMA16(vf[dt][1], pt1, oaccT[band][dt]);
                }
            }
        }
        __syncthreads();   // DMA drained + all readers of buf[p] done
    }

    // ---- reduce row sums across quads, normalize, store O (ushort4 on d) ----
#pragma unroll
    for (int band = 0; band < 2; ++band) {
        float l = lacc[band];
        l += __shfl_xor(l, 16);
        l += __shfl_xor(l, 32);
        float inv = 1.0f / l;
        int m = 32 * w + 16 * band + li;        // qrow
#pragma unroll
        for (int dt = 0; dt < 4; ++dt) {
            ushort4 o4;
            o4.x = f2bf(oaccT[band][dt][0] * inv);
            o4.y = f2bf(oaccT[band][dt][1] * inv);
            o4.z = f2bf(oaccT[band][dt][2] * inv);
            o4.w = f2bf(oaccT[band][dt][3] * inv);
            *(ushort4*)(obase + (size_t)m * DIMM + 16 * dt + quad * 4) = o4;
        }
    }
}

// ---------------------------------------------------------------------------
extern "C" void kernel_launch(void* const* d_in, const int* in_sizes, int n_in,
                              void* d_out, int out_size, void* d_ws, size_t ws_size,
                              hipStream_t stream)
{
    const float* x    = (const float*)d_in[0];
    const float* Wqkv = (const float*)d_in[1];
    const float* bqkv = (const float*)d_in[2];
    const float* Wout = (const float*)d_in[3];
    const float* bout = (const float*)d_in[4];

    const size_t M4 = (size_t)4 * 1024 * 1024;
    ushortT* ws  = (ushortT*)d_ws;
    ushortT* xb  = ws;                                  // 4M shorts
    ushortT* qb  = ws + M4;                             // 4M
    ushortT* kb  = ws + 2 * M4;                         // 4M
    ushortT* vt  = ws + 3 * M4;                         // 4M  [B,H,d,L]
    ushortT* ob  = ws + 4 * M4;                         // 4M  [B,L,H*d]
    ushortT* wqt = ws + 5 * M4;                         // 3M
    ushortT* wot = ws + 5 * M4 + (size_t)3 * 1024 * 1024;  // 1M

    prep<<<8192, 256, 0, stream>>>(x, xb, Wqkv, Wout, wqt, wot);
    gemm_qkv<<<dim3(24, 32), 256, 0, stream>>>(xb, wqt, bqkv, qb, kb, vt);
    attn<<<dim3(512), 256, 0, stream>>>(qb, kb, vt, ob);
    gemm_out<<<dim3(16, 32), 256, 0, stream>>>(ob, wot, bout, (float*)d_out);
}

// Round 9
// 174.166 us; speedup vs baseline: 1.6982x; 1.6982x over previous
//
#include <hip/hip_runtime.h>
#include <math.h>

#define BATCH 2
#define LSEQ  2048
#define DIMM  1024
#define NH    16
#define DH    64

typedef unsigned short ushortT;
typedef __attribute__((ext_vector_type(8))) short bf16x8;
typedef __attribute__((ext_vector_type(4))) float f32x4;

#define MFMA16(a, b, c) __builtin_amdgcn_mfma_f32_16x16x32_bf16((a), (b), (c), 0, 0, 0)

// scale folded into q columns of W_qkv: (1/sqrt(64)) * log2(e)
#define QSCALE 0.18033688011112042f

__device__ __forceinline__ ushortT f2bf(float f) {
    unsigned u = __float_as_uint(f);
    u += 0x7fffu + ((u >> 16) & 1u);   // RNE
    return (ushortT)(u >> 16);
}

// async global->LDS, 16B per lane. LDS dest is wave-uniform base + lane*16.
// NOTE (R8 lesson): register-prefetch staging spills to scratch (WRITE_SIZE
// 10x output, VGPR stays ~112) — keep DMA staging.
__device__ __forceinline__ void gll16(const ushortT* g, ushortT* l) {
    ushortT* gm = const_cast<ushortT*>(g);
    __builtin_amdgcn_global_load_lds(
        (__attribute__((address_space(1))) void*)gm,
        (__attribute__((address_space(3))) void*)l, 16, 0, 0);
}

// ---------------------------------------------------------------------------
// Fused prep: blocks [0,4096): x fp32->bf16; blocks [4096,8192): weight
// transposes W[K][N] fp32 -> Wt[N][K] bf16 (q-cols of W_qkv scaled by QSCALE).
// ---------------------------------------------------------------------------
__global__ __launch_bounds__(256) void prep(
    const float* __restrict__ x, ushortT* __restrict__ xb,
    const float* __restrict__ Wqkv, const float* __restrict__ Wout,
    ushortT* __restrict__ wqt, ushortT* __restrict__ wot)
{
    __shared__ float T[32][33];
    const int bx = blockIdx.x;
    const int tid = threadIdx.x;
    if (bx < 4096) {
        int i = bx * 256 + tid;
        float4 v = ((const float4*)x)[i];
        ushort4 o;
        o.x = f2bf(v.x); o.y = f2bf(v.y); o.z = f2bf(v.z); o.w = f2bf(v.w);
        ((ushort4*)xb)[i] = o;
        return;
    }
    const int id2 = bx - 4096;
    const int nb = id2 & 127, kb = id2 >> 7;
    const float* W; ushortT* Wt; int N, n0, nlimit;
    if (nb < 96) { W = Wqkv; Wt = wqt; N = 3 * DIMM; n0 = nb * 32; nlimit = DIMM; }
    else         { W = Wout; Wt = wot; N = DIMM;     n0 = (nb - 96) * 32; nlimit = 0; }
    const int k0 = kb * 32;
    const int c = tid & 31, r0 = tid >> 5;
#pragma unroll
    for (int p = 0; p < 4; ++p)
        T[r0 + 8 * p][c] = W[(size_t)(k0 + r0 + 8 * p) * N + n0 + c];
    __syncthreads();
#pragma unroll
    for (int p = 0; p < 4; ++p) {
        int rr = r0 + 8 * p;
        float v = T[c][rr];
        if (n0 + rr < nlimit) v *= QSCALE;
        Wt[(size_t)(n0 + rr) * DIMM + k0 + c] = f2bf(v);
    }
}

// ---------------------------------------------------------------------------
// 128x128 GEMM mainloop (m97-style DMA staging), templated on operand swap:
// SWAP=false: acc rows = A(m) rows; SWAP=true: acc rows = Bt(n) rows (C^T).
// ---------------------------------------------------------------------------
template<bool SWAP>
__device__ __forceinline__ void mainloop128(
    const ushortT* __restrict__ A, const ushortT* __restrict__ Bt,
    ushortT* As, ushortT* Bs, int bm, int bn,
    int w, int lane, int quad, int li, f32x4 acc[4][4])
{
    const int wr = (w & 1) * 64, wc = (w >> 1) * 64;
    const int rsub = lane >> 3, csub = lane & 7;
    const int cch = csub ^ rsub;           // swizzled source chunk
    const int sw = li & 7;
    const int s0 = (quad ^ sw) * 8;
    const int s1 = ((quad + 4) ^ sw) * 8;

    const ushortT* pa[4]; const ushortT* pb[4];
    ushortT* la[4]; ushortT* lb[4];
#pragma unroll
    for (int j = 0; j < 4; ++j) {
        int r = (w * 4 + j) * 8 + rsub;
        pa[j] = A  + (size_t)(bm + r) * DIMM + cch * 8;
        pb[j] = Bt + (size_t)(bn + r) * DIMM + cch * 8;
        la[j] = As + (w * 4 + j) * 512;
        lb[j] = Bs + (w * 4 + j) * 512;
    }
    const ushortT* RS = SWAP ? Bs : As;    // row-operand source
    const ushortT* CS = SWAP ? As : Bs;    // col-operand source

    for (int k0 = 0; k0 < DIMM; k0 += 64) {
#pragma unroll
        for (int j = 0; j < 4; ++j) {
            gll16(pa[j], la[j]);
            gll16(pb[j], lb[j]);
            pa[j] += 64; pb[j] += 64;
        }
        __syncthreads();
        bf16x8 bfr[4][2];
#pragma unroll
        for (int t = 0; t < 4; ++t) {
            int R = wc + 16 * t + li;
            bfr[t][0] = *(const bf16x8*)&CS[R * 64 + s0];
            bfr[t][1] = *(const bf16x8*)&CS[R * 64 + s1];
        }
#pragma unroll
        for (int rt = 0; rt < 4; ++rt) {
            int R = wr + 16 * rt + li;
            bf16x8 a0 = *(const bf16x8*)&RS[R * 64 + s0];
            bf16x8 a1 = *(const bf16x8*)&RS[R * 64 + s1];
#pragma unroll
            for (int ct = 0; ct < 4; ++ct) {
                acc[rt][ct] = MFMA16(a0, bfr[ct][0], acc[rt][ct]);
                acc[rt][ct] = MFMA16(a1, bfr[ct][1], acc[rt][ct]);
            }
        }
        __syncthreads();
    }
}

// ---------------------------------------------------------------------------
// GEMM1: qkv projection. q/k via swapped mainloop -> vectorized [b,h,l,d]
// stores; v via normal mainloop -> vectorized transposed [b,h,d,l] stores.
// ---------------------------------------------------------------------------
__global__ __launch_bounds__(256) void gemm_qkv(
    const ushortT* __restrict__ A, const ushortT* __restrict__ Bt,
    const float* __restrict__ bias,
    ushortT* __restrict__ qb, ushortT* __restrict__ kb, ushortT* __restrict__ vt)
{
    __shared__ __align__(16) ushortT As[128 * 64];
    __shared__ __align__(16) ushortT Bs[128 * 64];
    const int tid = threadIdx.x;
    const int w = tid >> 6, lane = tid & 63, quad = lane >> 4, li = lane & 15;
    const int bm = blockIdx.y * 128, bn = blockIdx.x * 128;
    const int wr = (w & 1) * 64, wc = (w >> 1) * 64;
    const int which = bn >> 10;                       // 0=q 1=k 2=v (uniform)
    const f32x4 z4 = {0.f, 0.f, 0.f, 0.f};
    f32x4 acc[4][4];
#pragma unroll
    for (int i = 0; i < 4; ++i)
#pragma unroll
        for (int j = 0; j < 4; ++j) acc[i][j] = z4;

    if (which == 2) {
        mainloop128<false>(A, Bt, As, Bs, bm, bn, w, lane, quad, li, acc);
#pragma unroll
        for (int rt = 0; rt < 4; ++rt) {
            int m = bm + wr + 16 * rt + quad * 4;
            int b = m >> 11, l = m & 2047;
#pragma unroll
            for (int ct = 0; ct < 4; ++ct) {
                int n = bn + wc + 16 * ct + li;
                float bterm = bias[n];
                int h = (n >> 6) & 15, dd = n & 63;
                ushort4 o4;
                o4.x = f2bf(acc[rt][ct][0] + bterm);
                o4.y = f2bf(acc[rt][ct][1] + bterm);
                o4.z = f2bf(acc[rt][ct][2] + bterm);
                o4.w = f2bf(acc[rt][ct][3] + bterm);
                *(ushort4*)(vt + ((size_t)(b * NH + h) * DH + dd) * LSEQ + l) = o4;
            }
        }
    } else {
        mainloop128<true>(A, Bt, As, Bs, bm, bn, w, lane, quad, li, acc);
        const float bscale = (which == 0) ? QSCALE : 1.0f;
        ushortT* dst = (which == 0) ? qb : kb;
#pragma unroll
        for (int rt = 0; rt < 4; ++rt) {
            int n0 = bn + wr + 16 * rt + quad * 4;   // 4 consecutive n
            int h = (n0 >> 6) & 15, dd = n0 & 63;
            float4 bv = *(const float4*)&bias[n0];
#pragma unroll
            for (int ct = 0; ct < 4; ++ct) {
                int m = bm + wc + 16 * ct + li;
                int b = m >> 11, l = m & 2047;
                ushort4 o4;
                o4.x = f2bf(acc[rt][ct][0] + bv.x * bscale);
                o4.y = f2bf(acc[rt][ct][1] + bv.y * bscale);
                o4.z = f2bf(acc[rt][ct][2] + bv.z * bscale);
                o4.w = f2bf(acc[rt][ct][3] + bv.w * bscale);
                *(ushort4*)(dst + ((size_t)(b * NH + h) * LSEQ + l) * DH + dd) = o4;
            }
        }
    }
}

// ---------------------------------------------------------------------------
// GEMM2: out = o @ W_out + b_out (fp32 out). 128(M)x64(N) tiles, BK=128,
// DMA staging (R7 version — register prefetch spilled, see R8).
// ---------------------------------------------------------------------------
__global__ __launch_bounds__(256) void gemm_out(
    const ushortT* __restrict__ A, const ushortT* __restrict__ Bt,
    const float* __restrict__ bias, float* __restrict__ out)
{
    __shared__ __align__(16) ushortT As[128 * 128];   // 32 KB
    __shared__ __align__(16) ushortT Bs[64 * 128];    // 16 KB
    const int tid = threadIdx.x;
    const int w = tid >> 6, lane = tid & 63, quad = lane >> 4, li = lane & 15;
    const int bm = blockIdx.y * 128, bn = blockIdx.x * 64;
    const int wm = (w & 1) * 64, wn = (w >> 1) * 32;
    const int r4 = lane >> 4, c16 = lane & 15;
    const int sw = li & 7;

    const ushortT* pa[8]; ushortT* la[8];
#pragma unroll
    for (int j = 0; j < 8; ++j) {
        int Bi = w + 4 * j;
        int row = Bi * 4 + r4;
        int cxA = c16 ^ ((Bi & 1) * 4 + r4);       // == c16 ^ (row&7)
        pa[j] = A + (size_t)(bm + row) * DIMM + cxA * 8;
        la[j] = As + Bi * 512;
    }
    const ushortT* pb[4]; ushortT* lb[4];
#pragma unroll
    for (int j = 0; j < 4; ++j) {
        int Bi = w + 4 * j;
        int row = Bi * 4 + r4;
        int cxB = c16 ^ ((Bi & 1) * 4 + r4);
        pb[j] = Bt + (size_t)(bn + row) * DIMM + cxB * 8;
        lb[j] = Bs + Bi * 512;
    }

    const f32x4 z4 = {0.f, 0.f, 0.f, 0.f};
    f32x4 acc[4][2];
#pragma unroll
    for (int i = 0; i < 4; ++i) { acc[i][0] = z4; acc[i][1] = z4; }

    for (int k0 = 0; k0 < DIMM; k0 += 128) {
#pragma unroll
        for (int j = 0; j < 8; ++j) { gll16(pa[j], la[j]); pa[j] += 128; }
#pragma unroll
        for (int j = 0; j < 4; ++j) { gll16(pb[j], lb[j]); pb[j] += 128; }
        __syncthreads();
#pragma unroll
        for (int g = 0; g < 2; ++g) {
            const int s0 = (g * 8 + (quad ^ sw)) * 8;
            const int s1 = (g * 8 + ((quad + 4) ^ sw)) * 8;
            bf16x8 bfr[2][2];
#pragma unroll
            for (int t = 0; t < 2; ++t) {
                int R = wn + 16 * t + li;
                bfr[t][0] = *(const bf16x8*)&Bs[R * 128 + s0];
                bfr[t][1] = *(const bf16x8*)&Bs[R * 128 + s1];
            }
#pragma unroll
            for (int rt = 0; rt < 4; ++rt) {
                int R = wm + 16 * rt + li;
                bf16x8 a0 = *(const bf16x8*)&As[R * 128 + s0];
                bf16x8 a1 = *(const bf16x8*)&As[R * 128 + s1];
#pragma unroll
                for (int ct = 0; ct < 2; ++ct) {
                    acc[rt][ct] = MFMA16(a0, bfr[ct][0], acc[rt][ct]);
                    acc[rt][ct] = MFMA16(a1, bfr[ct][1], acc[rt][ct]);
                }
            }
        }
        __syncthreads();
    }
#pragma unroll
    for (int rt = 0; rt < 4; ++rt) {
#pragma unroll
        for (int ct = 0; ct < 2; ++ct) {
            int n = bn + wn + 16 * ct + li;
            float bterm = bias[n];
#pragma unroll
            for (int r = 0; r < 4; ++r) {
                int m = bm + wm + 16 * rt + quad * 4 + r;
                out[(size_t)m * DIMM + n] = acc[rt][ct][r] + bterm;
            }
        }
    }
}

// ---------------------------------------------------------------------------
// Flash attention, block-causal, transposed inner math, 128-KEY TILES.
// R9: softmax denominators computed by MFMA (A = ones, B = P^T fragments
// already loaded for PV) — removes the per-element AND+fadd chain and the
// final shuffle reduction; sum is exactly consistent with stored bf16 P.
// P packing via v_perm_b32 (1 op per pair).
// ---------------------------------------------------------------------------
__global__ __launch_bounds__(256, 2) void attn(
    const ushortT* __restrict__ qg, const ushortT* __restrict__ kg,
    const ushortT* __restrict__ vtg, ushortT* __restrict__ og)
{
    __shared__ __align__(16) ushortT Kbuf[2][8192];   // [p][half*4096 + blk*512]
    __shared__ __align__(16) ushortT Vbuf[2][8192];   // [d][l] halves
    __shared__ __align__(16) ushortT PsT[4096];       // 4 waves x 2 KB

    const int tid = threadIdx.x;
    const int w = tid >> 6, lane = tid & 63, quad = lane >> 4, li = lane & 15;
    const int id = blockIdx.x;                 // 0..511
    const int qt = (id < 256) ? (15 - (id >> 5)) : ((id - 256) >> 5);
    const int bhid = id & 31;
    const int b = bhid >> 4, h = bhid & 15;
    const size_t bh = (size_t)b * NH + h;
    const ushortT* qbase = qg + (bh * LSEQ + qt * 128) * DH;
    const ushortT* kbase = kg + bh * LSEQ * DH;
    const ushortT* vbase = vtg + bh * DH * LSEQ;
    ushortT* obase = og + ((size_t)b * LSEQ + qt * 128) * DIMM + h * DH;
    const f32x4 z4 = {0.f, 0.f, 0.f, 0.f};

    // ones A-fragment for the denominator MFMA (bf16 1.0 = 0x3F80)
    const short ONE = (short)0x3F80;
    const bf16x8 onesA = {ONE, ONE, ONE, ONE, ONE, ONE, ONE, ONE};

    // staging lane geometry (within each 8-row x 1KB DMA block)
    const int r8 = lane >> 3, c8 = lane & 7, cx = c8 ^ r8;

    bf16x8 qf[2][2];
#pragma unroll
    for (int band = 0; band < 2; ++band) {
        int row = 32 * w + 16 * band + li;
        qf[band][0] = *(const bf16x8*)(qbase + (size_t)row * DH + quad * 8);
        qf[band][1] = *(const bf16x8*)(qbase + (size_t)row * DH + 32 + quad * 8);
    }
    f32x4 oaccT[2][4];     // [band][dt]: O^T, lane owns qrow=li
    f32x4 lsacc[2];        // denominator acc (all 4 comps equal per lane)
#pragma unroll
    for (int i = 0; i < 2; ++i) {
        lsacc[i] = z4;
#pragma unroll
        for (int j = 0; j < 4; ++j) oaccT[i][j] = z4;
    }

    const int nt = qt + 1;                 // 128-key tiles
    // stage tile 0 (8 gll16/wave: 2 halves x {K,V} x 2 blocks)
#pragma unroll
    for (int s = 0; s < 2; ++s)
#pragma unroll
        for (int jj = 0; jj < 2; ++jj) {
            int B = w + 4 * jj;
            gll16(kbase + (size_t)(s * 64 + B * 8 + r8) * DH + cx * 8,
                  &Kbuf[0][s * 4096 + B * 512]);
            gll16(vbase + (size_t)(B * 8 + r8) * LSEQ + s * 64 + cx * 8,
                  &Vbuf[0][s * 4096 + B * 512]);
        }
    __syncthreads();

    const int sw = li & 7;
    const int pbase = w * 1024 + li * 8;

    for (int t = 0; t < nt; ++t) {
        const int p = t & 1;
        if (t + 1 < nt) {   // DMA next 128-key tile; drains at loop barrier
#pragma unroll
            for (int s = 0; s < 2; ++s)
#pragma unroll
                for (int jj = 0; jj < 2; ++jj) {
                    int B = w + 4 * jj;
                    gll16(kbase + (size_t)((t + 1) * 128 + s * 64 + B * 8 + r8) * DH + cx * 8,
                          &Kbuf[1 - p][s * 4096 + B * 512]);
                    gll16(vbase + (size_t)(B * 8 + r8) * LSEQ + (t + 1) * 128 + s * 64 + cx * 8,
                          &Vbuf[1 - p][s * 4096 + B * 512]);
                }
        }

#pragma unroll
        for (int s = 0; s < 2; ++s) {
            const ushortT* Kb = &Kbuf[p][s * 4096];
            const ushortT* Vb = &Vbuf[p][s * 4096];
            bf16x8 kf[4][2], vf[4][2];
#pragma unroll
            for (int ct = 0; ct < 4; ++ct) {
                int R = 16 * ct + li;
                kf[ct][0] = *(const bf16x8*)&Kb[R * 64 + (quad ^ sw) * 8];
                kf[ct][1] = *(const bf16x8*)&Kb[R * 64 + ((quad + 4) ^ sw) * 8];
            }
#pragma unroll
            for (int dt = 0; dt < 4; ++dt) {
                int R = 16 * dt + li;
                vf[dt][0] = *(const bf16x8*)&Vb[R * 64 + (quad ^ sw) * 8];
                vf[dt][1] = *(const bf16x8*)&Vb[R * 64 + ((quad + 4) ^ sw) * 8];
            }
#pragma unroll
            for (int band = 0; band < 2; ++band) {
                // S^T = K Q^T (pre-scaled, log2 domain)
                f32x4 sa[4];
#pragma unroll
                for (int ct = 0; ct < 4; ++ct) {
                    sa[ct] = MFMA16(kf[ct][0], qf[band][0], z4);
                    sa[ct] = MFMA16(kf[ct][1], qf[band][1], sa[ct]);
                }
                // exp2, pack 4 keys (RTZ bf16) via v_perm, one b64 write
#pragma unroll
                for (int ct = 0; ct < 4; ++ct) {
                    unsigned u0 = __float_as_uint(__builtin_amdgcn_exp2f(sa[ct][0]));
                    unsigned u1 = __float_as_uint(__builtin_amdgcn_exp2f(sa[ct][1]));
                    unsigned u2 = __float_as_uint(__builtin_amdgcn_exp2f(sa[ct][2]));
                    unsigned u3 = __float_as_uint(__builtin_amdgcn_exp2f(sa[ct][3]));
                    uint2 pk;
                    pk.x = __builtin_amdgcn_perm(u1, u0, 0x07060302u);
                    pk.y = __builtin_amdgcn_perm(u3, u2, 0x07060302u);
                    *(uint2*)&PsT[pbase + (2 * ct + (quad >> 1)) * 128 + (quad & 1) * 4] = pk;
                }
                // read P^T fragments once; use for BOTH denominator and PV
                bf16x8 pt0 = *(const bf16x8*)&PsT[pbase + quad * 128];
                bf16x8 pt1 = *(const bf16x8*)&PsT[pbase + (4 + quad) * 128];
                lsacc[band] = MFMA16(onesA, pt0, lsacc[band]);   // denom += col-sums
                lsacc[band] = MFMA16(onesA, pt1, lsacc[band]);
#pragma unroll
                for (int dt = 0; dt < 4; ++dt) {
                    oaccT[band][dt] = MFMA16(vf[dt][0], pt0, oaccT[band][dt]);
                    oaccT[band][dt] = MFMA16(vf[dt][1], pt1, oaccT[band][dt]);
                }
            }
        }
        __syncthreads();   // DMA drained + all readers of buf[p] done
    }

    // ---- normalize (denominator complete per-lane), store O (ushort4 on d) ----
#pragma unroll
    for (int band = 0; band < 2; ++band) {
        float inv = 1.0f / lsacc[band][0];
        int m = 32 * w + 16 * band + li;        // qrow
#pragma unroll
        for (int dt = 0; dt < 4; ++dt) {
            ushort4 o4;
            o4.x = f2bf(oaccT[band][dt][0] * inv);
            o4.y = f2bf(oaccT[band][dt][1] * inv);
            o4.z = f2bf(oaccT[band][dt][2] * inv);
            o4.w = f2bf(oaccT[band][dt][3] * inv);
            *(ushort4*)(obase + (size_t)m * DIMM + 16 * dt + quad * 4) = o4;
        }
    }
}

// ---------------------------------------------------------------------------
extern "C" void kernel_launch(void* const* d_in, const int* in_sizes, int n_in,
                              void* d_out, int out_size, void* d_ws, size_t ws_size,
                              hipStream_t stream)
{
    const float* x    = (const float*)d_in[0];
    const float* Wqkv = (const float*)d_in[1];
    const float* bqkv = (const float*)d_in[2];
    const float* Wout = (const float*)d_in[3];
    const float* bout = (const float*)d_in[4];

    const size_t M4 = (size_t)4 * 1024 * 1024;
    ushortT* ws  = (ushortT*)d_ws;
    ushortT* xb  = ws;                                  // 4M shorts
    ushortT* qb  = ws + M4;                             // 4M
    ushortT* kb  = ws + 2 * M4;                         // 4M
    ushortT* vt  = ws + 3 * M4;                         // 4M  [B,H,d,L]
    ushortT* ob  = ws + 4 * M4;                         // 4M  [B,L,H*d]
    ushortT* wqt = ws + 5 * M4;                         // 3M
    ushortT* wot = ws + 5 * M4 + (size_t)3 * 1024 * 1024;  // 1M

    prep<<<8192, 256, 0, stream>>>(x, xb, Wqkv, Wout, wqt, wot);
    gemm_qkv<<<dim3(24, 32), 256, 0, stream>>>(xb, wqt, bqkv, qb, kb, vt);
    attn<<<dim3(512), 256, 0, stream>>>(qb, kb, vt, ob);
    gemm_out<<<dim3(16, 32), 256, 0, stream>>>(ob, wot, bout, (float*)d_out);
}